// Round 6
// baseline (349.086 us; speedup 1.0000x reference)
//
#include <hip/hip_runtime.h>
#include <hip/hip_bf16.h>

#define BTOK 8192
#define DDIM 1024
#define NEXP 8

typedef unsigned short u16;
typedef unsigned int u32;
typedef __attribute__((ext_vector_type(8))) short short8;
typedef __attribute__((ext_vector_type(4))) float f32x4;

constexpr int BM = 256, BN = 256, BK = 64;
constexpr int SLOTCAP = 3072;
constexpr int NT = DDIM / BK;          // 16 K-tiles

__device__ __forceinline__ u16 f2bf(float f){
  __hip_bfloat16 h = __float2bfloat16(f);
  return *reinterpret_cast<u16*>(&h);
}
__device__ __forceinline__ float bf2f(u16 v){
  return __uint_as_float(((u32)v) << 16);
}
__device__ __forceinline__ void gll16(const u16* gsrc, u16* ldst){
  __builtin_amdgcn_global_load_lds((const __attribute__((address_space(1))) void*)gsrc,
                                   (__attribute__((address_space(3))) void*)ldst,
                                   16, 0, 0);
}

// ---------------- gating score: h[t][e], fused x->bf16 cast ----------------
#define GTOK 16
__global__ __launch_bounds__(512) void gating_score_kernel(
    const float* __restrict__ x, const float* __restrict__ noise,
    const float* __restrict__ Wg, const float* __restrict__ Wn,
    float* __restrict__ h_out, u16* __restrict__ xb)
{
  __shared__ float lw[2][NEXP][4][260];
  const int tid = threadIdx.x;

  for (int i = tid; i < 2*DDIM*NEXP; i += 512){
    const int mat = i >> 13;
    const int r   = i & 8191;          // r = d*8 + e
    const int d = r >> 3, ee = r & 7;
    const float* W = mat ? Wn : Wg;
    lw[mat][ee][d >> 8][d & 255] = W[r];
  }
  __syncthreads();

  const int q   = tid & 3;
  const int e   = (tid >> 2) & 7;
  const int tok = tid >> 5;
  const int t   = blockIdx.x * GTOK + tok;

  const float4* x4 = reinterpret_cast<const float4*>(x + (size_t)t*DDIM + q*256);
  const float4* g4 = reinterpret_cast<const float4*>(&lw[0][e][q][0]);
  const float4* n4 = reinterpret_cast<const float4*>(&lw[1][e][q][0]);
  ushort4* xb4 = reinterpret_cast<ushort4*>(xb + (size_t)t*DDIM + q*256);
  float agx=0.f, agz=0.f, anx=0.f, anz=0.f;   // split chains for ILP
  #pragma unroll 8
  for (int j = 0; j < 64; ++j){
    const float4 xv = x4[j];
    const float4 wg = g4[j];
    const float4 wn = n4[j];
    agx = fmaf(xv.x,wg.x, fmaf(xv.y,wg.y, agx));
    agz = fmaf(xv.z,wg.z, fmaf(xv.w,wg.w, agz));
    anx = fmaf(xv.x,wn.x, fmaf(xv.y,wn.y, anx));
    anz = fmaf(xv.z,wn.z, fmaf(xv.w,wn.w, anz));
    if (e == 0)  // 8 lanes/wave also emit the bf16 cast of x (x already in regs)
      xb4[j] = make_ushort4(f2bf(xv.x), f2bf(xv.y), f2bf(xv.z), f2bf(xv.w));
  }
  float ag = agx + agz, an = anx + anz;
  ag += __shfl_xor(ag, 1); an += __shfl_xor(an, 1);
  ag += __shfl_xor(ag, 2); an += __shfl_xor(an, 2);
  if (q == 0){
    const float sp = (an > 20.f) ? an : log1pf(expf(an));
    h_out[(size_t)t*NEXP + e] = ag + noise[(size_t)t*NEXP + e] + sp;
  }
}

// ---------------- gating select: top-k, softmax, hierarchical slot alloc ----------------
__global__ __launch_bounds__(256) void gating_select_kernel(
    const float* __restrict__ h_in, const int* __restrict__ kp,
    float* __restrict__ gates, int* __restrict__ counts, int* __restrict__ lists,
    int* __restrict__ tokmap, int* __restrict__ ncnt)
{
  __shared__ int lcnt[NEXP];
  __shared__ int lbase[NEXP];
  const int tid = threadIdx.x;
  const int t   = blockIdx.x*256 + tid;
  if (tid < NEXP) lcnt[tid] = 0;
  __syncthreads();

  float h[NEXP];
  const float4 h0 = reinterpret_cast<const float4*>(h_in + (size_t)t*NEXP)[0];
  const float4 h1 = reinterpret_cast<const float4*>(h_in + (size_t)t*NEXP)[1];
  h[0]=h0.x; h[1]=h0.y; h[2]=h0.z; h[3]=h0.w;
  h[4]=h1.x; h[5]=h1.y; h[6]=h1.z; h[7]=h1.w;

  int kk = *kp; kk = kk<1?1:(kk>NEXP?NEXP:kk);
  bool used[NEXP];
  #pragma unroll
  for (int e=0;e<NEXP;e++) used[e]=false;
  float kth = 0.f;
  for (int i=0;i<kk;i++){
    int bi=0; float bv=-3.4e38f;
    #pragma unroll
    for (int e=0;e<NEXP;e++) if (!used[e] && h[e]>bv){bv=h[e]; bi=e;}
    used[bi]=true; kth=bv;
  }
  float m=-3.4e38f;
  #pragma unroll
  for (int e=0;e<NEXP;e++) if (h[e]>=kth && h[e]>m) m=h[e];
  float p[NEXP], s=0.f;
  #pragma unroll
  for (int e=0;e<NEXP;e++){ p[e]=(h[e]>=kth)?expf(h[e]-m):0.f; s+=p[e]; }
  const float inv = 1.f/s;
  float g[NEXP];
  int lslot[NEXP];
  #pragma unroll
  for (int e=0;e<NEXP;e++){
    g[e] = p[e]*inv;
    gates[(size_t)t*NEXP + e] = g[e];
    if (g[e] > 0.f) lslot[e] = atomicAdd(&lcnt[e], 1);   // LDS atomic: on-CU
  }
  __syncthreads();
  if (tid < NEXP) lbase[tid] = atomicAdd(&counts[tid], lcnt[tid]);  // 8 global atomics/block
  __syncthreads();
  int idx = 0;
  #pragma unroll
  for (int e=0;e<NEXP;e++){
    if (g[e] > 0.f){
      const int slot = lbase[e] + lslot[e];
      lists[e*BTOK + slot] = t;
      tokmap[t*NEXP + idx] = (e << 13) | (slot & 8191);
      idx++;
    }
  }
  ncnt[t] = idx;
}

// ---------------- transpose+cast W1,W2 -> bf16 WT[e][n][k] ----------------
__global__ __launch_bounds__(256) void trans_kernel(
    const float* __restrict__ W1, const float* __restrict__ W2,
    u16* __restrict__ W1T, u16* __restrict__ W2T)
{
  __shared__ float tile[64][65];
  const int mz = blockIdx.z;
  const float* src = (mz < NEXP) ? (W1  + (size_t)mz*DDIM*DDIM) : (W2  + (size_t)(mz-NEXP)*DDIM*DDIM);
  u16*       dst = (mz < NEXP) ? (W1T + (size_t)mz*DDIM*DDIM) : (W2T + (size_t)(mz-NEXP)*DDIM*DDIM);
  const int r0 = blockIdx.x*64, c0 = blockIdx.y*64;
  const int tx = threadIdx.x & 63, ty = threadIdx.x >> 6;
  #pragma unroll
  for (int i=ty;i<64;i+=4)
    tile[i][tx] = src[(size_t)(r0+i)*DDIM + c0+tx];
  __syncthreads();
  #pragma unroll
  for (int i=ty;i<64;i+=4)
    dst[(size_t)(c0+i)*DDIM + r0+tx] = f2bf(tile[tx][i]);
}

// ---- expert FFN GEMM: 256x256xBK64, 8 waves, counted-vmcnt pipeline (T3+T4+T5) ----
// Ledger (per wave, per K-iter): stage 8 gll for tile kt+2 AFTER barrier (A);
// s_waitcnt vmcnt(8) drains only LAST iter's 8 (tile kt+1) and keeps this
// iter's 8 in flight across barrier (B). Prologue: stage t0,t1 (16 in flight),
// vmcnt(8) -> t0 ready. Tail (no stage): vmcnt(0).
template<int LAYER>
__device__ __forceinline__ void ffn_body(
    const u16* __restrict__ Asrc, const u16* __restrict__ WT,
    const float* __restrict__ bias,
    const int* __restrict__ counts, const int* __restrict__ lists,
    u16* __restrict__ dst)
{
  const int e  = blockIdx.z;
  int cnt = counts[e]; if (cnt > SLOTCAP) cnt = SLOTCAP;
  const int m0 = blockIdx.x*BM;
  if (m0 >= cnt) return;                 // uniform early-exit (before any barrier)
  const int n0 = blockIdx.y*BN;

  __shared__ __align__(16) u16 ldsA[2][BM*BK];   // 64 KB
  __shared__ __align__(16) u16 ldsB[2][BN*BK];   // 64 KB

  const int tid = threadIdx.x;
  const int wave = tid>>6, lane = tid&63;
  const int wm = wave>>2, wn = wave&3;           // 2M x 4N waves

  // staging sources (T2 both-sides rule: linear LDS dest, pre-swizzled global src)
  const u16* aSrc[4]; const u16* bSrc[4];
  {
    const int lr = lane>>3, sp = lane&7;
    #pragma unroll
    for (int i=0;i<4;i++){
      const int row = wave*32 + i*8 + lr;        // 0..255
      const int ku  = sp ^ (row&7);
      size_t abase;
      if constexpr (LAYER==1){
        int gr = m0 + row; if (gr >= cnt) gr = cnt-1;   // clamp: dup rows
        abase = (size_t)lists[e*BTOK + gr] * DDIM;
      } else {
        abase = ((size_t)e*SLOTCAP + m0 + row) * DDIM;
      }
      aSrc[i] = Asrc + abase + ku*8;
      bSrc[i] = WT + ((size_t)e*DDIM + n0 + row)*DDIM + ku*8;
    }
  }

  const int q = lane>>4, l16 = lane&15;
  // swizzled ds_read offsets (u16 units) for kk=0; kk=1 is ^32 (slot bit2 flip)
  int aoff[8], boff[4];
  #pragma unroll
  for (int f=0;f<8;f++){
    const int ra = wm*128 + f*16 + l16;
    aoff[f] = ra*BK + ((q ^ (ra&7))*8);
  }
  #pragma unroll
  for (int f=0;f<4;f++){
    const int rb = wn*64 + f*16 + l16;
    boff[f] = rb*BK + ((q ^ (rb&7))*8);
  }

  f32x4 acc[8][4];
  #pragma unroll
  for (int i=0;i<8;i++)
    #pragma unroll
    for (int j=0;j<4;j++)
      acc[i][j] = (f32x4){0.f,0.f,0.f,0.f};

  #define STAGE(T, c)                                            \
    _Pragma("unroll")                                            \
    for (int i=0;i<4;i++){                                       \
      gll16(aSrc[i] + (size_t)(T)*BK, &ldsA[c][(wave*32+i*8)*BK]); \
      gll16(bSrc[i] + (size_t)(T)*BK, &ldsB[c][(wave*32+i*8)*BK]); \
    }

  // prologue: stage tiles 0 and 1 (16 loads in flight), wait for tile 0 only
  STAGE(0, 0)
  STAGE(1, 1)
  asm volatile("s_waitcnt vmcnt(8)" ::: "memory");
  __builtin_amdgcn_sched_barrier(0);
  __builtin_amdgcn_s_barrier();
  __builtin_amdgcn_sched_barrier(0);

  for (int kt = 0; kt < NT; ++kt){
    const int c = kt & 1;
    // ---- compute tile kt from buf c ----
    #pragma unroll
    for (int kk=0; kk<2; kk++){
      const int kx = kk ? 32 : 0;
      short8 bfr[4], afr[8];
      #pragma unroll
      for (int f=0;f<4;f++) bfr[f] = *reinterpret_cast<const short8*>(&ldsB[c][boff[f] ^ kx]);
      #pragma unroll
      for (int f=0;f<8;f++) afr[f] = *reinterpret_cast<const short8*>(&ldsA[c][aoff[f] ^ kx]);
      __builtin_amdgcn_s_setprio(1);
      #pragma unroll
      for (int fm=0;fm<8;fm++)
        #pragma unroll
        for (int fn=0;fn<4;fn++)
          acc[fm][fn] = __builtin_amdgcn_mfma_f32_16x16x32_bf16(afr[fm], bfr[fn], acc[fm][fn], 0, 0, 0);
      __builtin_amdgcn_s_setprio(0);
    }
    // ---- barrier (A): all waves done reading buf c ----
    __builtin_amdgcn_sched_barrier(0);
    __builtin_amdgcn_s_barrier();
    __builtin_amdgcn_sched_barrier(0);
    // ---- stage tile kt+2 into buf c; wait only for tile kt+1's loads ----
    if (kt + 2 < NT){
      STAGE(kt+2, c)
      asm volatile("s_waitcnt vmcnt(8)" ::: "memory");
    } else {
      asm volatile("s_waitcnt vmcnt(0)" ::: "memory");
    }
    __builtin_amdgcn_sched_barrier(0);
    __builtin_amdgcn_s_barrier();          // (B): buf c^1 (tile kt+1) ready
    __builtin_amdgcn_sched_barrier(0);
  }
  #undef STAGE

  // epilogue: C/D layout col=lane&15, row=(lane>>4)*4+reg
  #pragma unroll
  for (int fm=0;fm<8;fm++){
    #pragma unroll
    for (int r=0;r<4;r++){
      const int row = wm*128 + fm*16 + q*4 + r;
      const int gr  = m0 + row;                 // < SLOTCAP by grid
      #pragma unroll
      for (int fn=0;fn<4;fn++){
        const int col = n0 + wn*64 + fn*16 + l16;
        float v = acc[fm][fn][r] + bias[e*DDIM + col];
        if constexpr (LAYER==1) v = v > 0.f ? v : 0.f;
        dst[((size_t)e*SLOTCAP + gr)*DDIM + col] = f2bf(v);
      }
    }
  }
}

__global__ __launch_bounds__(512, 2) void ffn1_kernel(
    const u16* __restrict__ A, const u16* __restrict__ WT, const float* __restrict__ b,
    const int* __restrict__ counts, const int* __restrict__ lists, u16* __restrict__ dst)
{ ffn_body<1>(A, WT, b, counts, lists, dst); }

__global__ __launch_bounds__(512, 2) void ffn2_kernel(
    const u16* __restrict__ A, const u16* __restrict__ WT, const float* __restrict__ b,
    const int* __restrict__ counts, const int* __restrict__ lists, u16* __restrict__ dst)
{ ffn_body<2>(A, WT, b, counts, lists, dst); }

// ---------------- combine ----------------
__global__ __launch_bounds__(256) void combine_kernel(
    const u16* __restrict__ partial, const int* __restrict__ tokmap,
    const int* __restrict__ ncnt, const float* __restrict__ gates,
    float* __restrict__ out)
{
  const int t = blockIdx.x, c = threadIdx.x;
  const int n = ncnt[t];
  float4 acc = {0.f, 0.f, 0.f, 0.f};
  for (int j = 0; j < n; ++j){
    const int ent  = tokmap[t*NEXP + j];
    const int e    = ent >> 13, slot = ent & 8191;
    if (slot >= SLOTCAP) continue;
    const float g = gates[(size_t)t*NEXP + e];
    const ushort4 pv = reinterpret_cast<const ushort4*>(
        partial + ((size_t)e*SLOTCAP + slot)*DDIM)[c];
    acc.x = fmaf(g, bf2f(pv.x), acc.x);
    acc.y = fmaf(g, bf2f(pv.y), acc.y);
    acc.z = fmaf(g, bf2f(pv.z), acc.z);
    acc.w = fmaf(g, bf2f(pv.w), acc.w);
  }
  reinterpret_cast<float4*>(out + (size_t)t*DDIM)[c] = acc;
}

// ---------------- host launch ----------------
extern "C" void kernel_launch(void* const* d_in, const int* in_sizes, int n_in,
                              void* d_out, int out_size, void* d_ws, size_t ws_size,
                              hipStream_t stream)
{
  const float* x     = (const float*)d_in[0];
  const float* noise = (const float*)d_in[1];
  const float* Wg    = (const float*)d_in[2];
  const float* Wn    = (const float*)d_in[3];
  const float* W1    = (const float*)d_in[4];
  const float* b1    = (const float*)d_in[5];
  const float* W2    = (const float*)d_in[6];
  const float* b2    = (const float*)d_in[7];
  const int*   kp    = (const int*)d_in[8];
  float* out = (float*)d_out;

  char* ws = (char*)d_ws;
  int*   counts = (int*)ws;                      // 4K
  int*   lists  = (int*)(ws + 4096);             // 256K
  float* gates  = (float*)(ws + 266240);         // 256K
  int*   tokmap = (int*)(ws + 528384);           // 256K
  int*   ncnt   = (int*)(ws + 790528);           // 32K
  float* hbuf   = (float*)(ws + 823296);         // 256K
  u16*   xb     = (u16*)(ws + 1085440);          // 16.78M
  u16*   W1T    = (u16*)(ws + 17862656);         // 16.78M
  u16*   W2T    = (u16*)(ws + 34639872);         // 16.78M
  u16*   hidden = (u16*)(ws + 51417088);         // 50.33M
  u16*   partial= (u16*)(ws + 101748736);        // 50.33M
  const size_t NEED = 152080384ull;

  hipMemsetAsync(counts, 0, 64, stream);
  if (ws_size < NEED){
    hipMemsetAsync(d_out, 0, (size_t)out_size*sizeof(float), stream);
    return;
  }

  trans_kernel<<<dim3(16,16,16), 256, 0, stream>>>(W1, W2, W1T, W2T);
  gating_score_kernel<<<BTOK/GTOK, 512, 0, stream>>>(x, noise, Wg, Wn, hbuf, xb);
  gating_select_kernel<<<BTOK/256, 256, 0, stream>>>(hbuf, kp, gates, counts, lists,
                                                     tokmap, ncnt);
  ffn1_kernel<<<dim3(SLOTCAP/BM, DDIM/BN, NEXP), 512, 0, stream>>>(
      xb, W1T, b1, counts, lists, hidden);
  ffn2_kernel<<<dim3(SLOTCAP/BM, DDIM/BN, NEXP), 512, 0, stream>>>(
      hidden, W2T, b2, counts, lists, partial);
  combine_kernel<<<BTOK, 256, 0, stream>>>(partial, tokmap, ncnt, gates, out);
}